// Round 18
// baseline (117.014 us; speedup 1.0000x reference)
//
#include <hip/hip_runtime.h>
#include <math.h>

#define NN 8192

typedef __attribute__((ext_vector_type(8))) short short8;
typedef __attribute__((ext_vector_type(4))) short short4v;
typedef __attribute__((ext_vector_type(4))) float f32x4;
typedef __attribute__((ext_vector_type(4))) int int4v;

#define L2E 1.4426950408889634f

typedef __attribute__((address_space(3))) unsigned lds_u32;
typedef __attribute__((address_space(1))) unsigned g_u32;

__device__ __forceinline__ void gll16(const void* g, void* l) {
    __builtin_amdgcn_global_load_lds((const g_u32*)g, (lds_u32*)l, 16, 0, 0);
}

__device__ __forceinline__ short f2bf(float f) {
    union { float f; unsigned u; } v; v.f = f;
    unsigned r = v.u + 0x7fffu + ((v.u >> 16) & 1u);
    return (short)(r >> 16);
}

__device__ __forceinline__ f32x4 zero4() {
    f32x4 v; v[0] = 0.f; v[1] = 0.f; v[2] = 0.f; v[3] = 0.f; return v;
}

// ---------- K0: WT[f][k] = bf16(W[k][f]) ----------
__global__ void k0_wt(const float* __restrict__ W, short* __restrict__ WT) {
    int idx = blockIdx.x * 256 + threadIdx.x;
    if (idx < 256 * 128) {
        int k = idx & 255;
        int f = idx >> 8;
        WT[f * 256 + k] = f2bf(W[k * 128 + f]);
    }
}

// ---------- K1: h = x@W (bf16 MFMA); s1L2E/s2L2E; hTb j-blocked ----------
// hTb layout: [j/64][128 f][j%64] bf16 (R17-verified blocked write).
__global__ __launch_bounds__(128) void k1_h(
        const float* __restrict__ x, const short* __restrict__ WT,
        const float* __restrict__ a, short* __restrict__ hTb,
        float* __restrict__ s1L2E, float* __restrict__ s2L2E) {
    const int w = threadIdx.x >> 6;
    const int l = threadIdx.x & 63;
    const int quad = l >> 4;
    const int fr = l & 15;
    const int i0 = blockIdx.x * 32 + w * 16;

    f32x4 acc[8];
#pragma unroll
    for (int t = 0; t < 8; ++t) acc[t] = zero4();

    const float* xrow = x + (size_t)(i0 + fr) * 256;
#pragma unroll
    for (int kk = 0; kk < 8; ++kk) {
        const int k0 = kk * 32 + quad * 8;
        f32x4 xa = *(const f32x4*)(xrow + k0);
        f32x4 xb = *(const f32x4*)(xrow + k0 + 4);
        short8 av;
#pragma unroll
        for (int e = 0; e < 4; ++e) { av[e] = f2bf(xa[e]); av[4 + e] = f2bf(xb[e]); }
#pragma unroll
        for (int t = 0; t < 8; ++t) {
            short8 bv = *(const short8*)(WT + (t * 16 + fr) * 256 + k0);
            acc[t] = __builtin_amdgcn_mfma_f32_16x16x32_bf16(av, bv, acc[t], 0, 0, 0);
        }
    }

    float s1p[4] = {0.f, 0.f, 0.f, 0.f};
    float s2p[4] = {0.f, 0.f, 0.f, 0.f};
#pragma unroll
    for (int t = 0; t < 8; ++t) {
        float a1v = a[t * 16 + fr];
        float a2v = a[128 + t * 16 + fr];
#pragma unroll
        for (int r = 0; r < 4; ++r) {
            s1p[r] += acc[t][r] * a1v;
            s2p[r] += acc[t][r] * a2v;
        }
    }
#pragma unroll
    for (int r = 0; r < 4; ++r) {
#pragma unroll
        for (int m = 1; m < 16; m <<= 1) {
            s1p[r] += __shfl_xor(s1p[r], m, 64);
            s2p[r] += __shfl_xor(s2p[r], m, 64);
        }
    }
    if (fr == 0) {
#pragma unroll
        for (int r = 0; r < 4; ++r) {
            const int i = i0 + quad * 4 + r;
            s1L2E[i] = s1p[r] * L2E;
            s2L2E[i] = s2p[r] * L2E;
        }
    }

    {
        const size_t tbase = (size_t)(i0 >> 6) * 8192 + (i0 & 63) + quad * 4;
#pragma unroll
        for (int t = 0; t < 8; ++t) {
            short4v hv;
#pragma unroll
            for (int r = 0; r < 4; ++r) hv[r] = f2bf(acc[t][r]);
            *(short4v*)(hTb + tbase + (size_t)(t * 16 + fr) * 64) = hv;
        }
    }
}

// ---------- K2: macro-staged 1KB-contiguous adj + direct-L2 bv ----------
// Block: 32 rows x JW cols (JSPLIT=2 -> 512 blocks = 2/CU). Per MACRO
// (256 cols): adj staged as 32 x 1KB CONTIGUOUS row-chunks (one gll each,
// per-gll-uniform 16B-unit XOR permutation for bank-free reads), double-
// buffered -> fixes the 256B/32KB-stride DRAM granularity that capped all
// fused variants at ~3.5 TB/s. bv/c load DIRECT from L2 (hTb blocked: 16
// 64B-lines per inst = contiguous-equivalent). ONE __syncthreads per macro:
// the stage it drains was issued a full macro (~2500cy >> HBM latency)
// earlier -> drain cost ~0 (R15's trap was 1-step=600cy distance). No
// manual vmcnt anywhere (R9/R10 class structurally excluded).
// Waves: 4-way K-split of each macro (2 K-slices of 32 cols each), all
// share the 32 rows (2 M-tiles, acc[2][8]); 4-way K-reduce epilogue (R16).
template<int JSPLIT, bool PARTIAL>
__global__ __launch_bounds__(256, 2) void k2_attn(
        const int* __restrict__ adj, const short* __restrict__ hTb,
        const float* __restrict__ s1g, const float* __restrict__ s2g,
        float* __restrict__ pvp, float* __restrict__ zp,
        float* __restrict__ out) {
    constexpr int JW = NN / JSPLIT;
    constexpr int NMAC = JW / 256;
    __shared__ __align__(16) char lds_c[2 * 32768 + 512];

    const int tid = threadIdx.x;
    const int w = tid >> 6;
    const int l = tid & 63;
    const int quad = l >> 4;
    const int fr = l & 15;
    const int rb = blockIdx.x / JSPLIT;
    const int jb = blockIdx.x % JSPLIT;
    const int r32 = rb * 32;
    const int jbb = jb * JW;

    const float S0 = s1g[r32 + fr];        // M-tile 0 rows
    const float S1 = s1g[r32 + 16 + fr];   // M-tile 1 rows

    // adj gll sources: wave w stages rows w*8+p (p=0..7; row&7 == p).
    // lane l reads 16B unit (l ^ p) of the row's 1KB macro-chunk (uniform
    // permutation within the SAME 1KB -> coalescing preserved).
    const char* asrc[8];
    {
        const char* abase = (const char*)adj;
#pragma unroll
        for (int p = 0; p < 8; ++p) {
            const int row = w * 8 + p;
            asrc[p] = abase + (size_t)(r32 + row) * (NN * 4) + (size_t)jbb * 4
                    + ((unsigned)(l ^ p) << 4);
        }
    }
    auto STAGE_ADJ = [&](int m, int buf) {
        char* ad = lds_c + buf * 32768 + (w * 8) * 1024;
        const size_t aof = (size_t)m * 1024;
#pragma unroll
        for (int p = 0; p < 8; ++p) gll16(asrc[p] + aof, ad + p * 1024);
    };

    f32x4 acc[2][8];
#pragma unroll
    for (int m = 0; m < 2; ++m)
#pragma unroll
        for (int t = 0; t < 8; ++t) acc[m][t] = zero4();
    float zacc0 = 0.f, zacc1 = 0.f;

    STAGE_ADJ(0, 0);
    __syncthreads();

    for (int mac = 0; mac < NMAC; ++mac) {
        if (mac + 1 < NMAC) STAGE_ADJ(mac + 1, (mac + 1) & 1);

        const char* ab = lds_c + (mac & 1) * 32768;
        const int j64 = jbb + mac * 256 + w * 64;              // wave's 64-col window
        const short* tilebase = hTb + (size_t)(j64 >> 6) * 8192;
        const unsigned swz = (unsigned)(fr & 7);

#pragma unroll
        for (int sl = 0; sl < 2; ++sl) {
            // bv direct from L2 (blocked tile: rows 128B apart, 16B/lane)
            short8 bv[8];
#pragma unroll
            for (int F = 0; F < 8; ++F)
                bv[F] = *(const short8*)(tilebase + (F * 16 + fr) * 64 + sl * 32 + quad * 8);
            const f32x4 c0 = *(const f32x4*)(s2g + j64 + sl * 32 + quad * 8);
            const f32x4 c1 = *(const f32x4*)(s2g + j64 + sl * 32 + quad * 8 + 4);

            // adj bits from LDS: rows fr, fr+16; 16B units XOR'd by fr&7
            const unsigned ch = (unsigned)(w * 16 + sl * 8 + quad * 2);
            const int4v g00 = *(const int4v*)(ab + fr * 1024 + ((ch ^ swz) << 4));
            const int4v g01 = *(const int4v*)(ab + fr * 1024 + (((ch + 1) ^ swz) << 4));
            const int4v g10 = *(const int4v*)(ab + (fr + 16) * 1024 + ((ch ^ swz) << 4));
            const int4v g11 = *(const int4v*)(ab + (fr + 16) * 1024 + (((ch + 1) ^ swz) << 4));

            short8 pa0, pa1;
            {
                float zs0 = 0.f, zs1 = 0.f;
#pragma unroll
                for (int e = 0; e < 8; ++e) {
                    const float cv = (e < 4) ? c0[e] : c1[e - 4];
                    const int gv0 = (e < 4) ? g00[e] : g01[e - 4];
                    const int gv1 = (e < 4) ? g10[e] : g11[e - 4];
                    const float u0 = S0 + cv;
                    const float u1 = S1 + cv;
                    const float t0 = fmaxf(u0, 0.2f * u0);   // lrelu in log2 space
                    const float t1 = fmaxf(u1, 0.2f * u1);
                    const float p0 = (gv0 > 0) ? exp2f(t0) : 0.f;
                    const float p1 = (gv1 > 0) ? exp2f(t1) : 0.f;
                    zs0 += p0; zs1 += p1;
                    pa0[e] = f2bf(p0);
                    pa1[e] = f2bf(p1);
                }
                zacc0 += zs0; zacc1 += zs1;
            }

#pragma unroll
            for (int F = 0; F < 8; ++F) {
                acc[0][F] = __builtin_amdgcn_mfma_f32_16x16x32_bf16(pa0, bv[F], acc[0][F], 0, 0, 0);
                acc[1][F] = __builtin_amdgcn_mfma_f32_16x16x32_bf16(pa1, bv[F], acc[1][F], 0, 0, 0);
            }
        }

        __syncthreads();   // stage(mac+1) landed long ago; buf (mac&1) reads done
    }

    // ---- epilogue (R16-verified): 4-way K-reduction, 16KB region ----
    zacc0 += __shfl_xor(zacc0, 16, 64);
    zacc0 += __shfl_xor(zacc0, 32, 64);
    zacc1 += __shfl_xor(zacc1, 16, 64);
    zacc1 += __shfl_xor(zacc1, 32, 64);
    float* red = (float*)lds_c;
    float* zb = (float*)(lds_c + 2 * 32768);
    if (l < 16) {
        zb[w * 32 + l] = zacc0;
        zb[w * 32 + 16 + l] = zacc1;
    }

#pragma unroll
    for (int ww = 1; ww < 4; ++ww) {
        if (w == ww) {
#pragma unroll
            for (int m = 0; m < 2; ++m)
#pragma unroll
                for (int t = 0; t < 8; ++t)
                    *(f32x4*)(red + ((m * 8 + t) * 64 + l) * 4) = acc[m][t];
        }
        __syncthreads();
        if (w == 0) {
#pragma unroll
            for (int m = 0; m < 2; ++m)
#pragma unroll
                for (int t = 0; t < 8; ++t)
                    acc[m][t] += *(const f32x4*)(red + ((m * 8 + t) * 64 + l) * 4);
        }
        __syncthreads();
    }

    if (w == 0) {
#pragma unroll
        for (int m = 0; m < 2; ++m) {
#pragma unroll
            for (int r = 0; r < 4; ++r) {
                const int irow = m * 16 + quad * 4 + r;
                float z = 0.f;
#pragma unroll
                for (int ww = 0; ww < 4; ++ww) z += zb[ww * 32 + irow];
                const int grow = r32 + irow;
                if (PARTIAL) {
                    if (fr == 0) zp[(size_t)jb * NN + grow] = z;
                    float* orow = pvp + ((size_t)jb * NN + grow) * 128;
#pragma unroll
                    for (int t = 0; t < 8; ++t) orow[t * 16 + fr] = acc[m][t][r];
                } else {
                    const float inv = 1.0f / z;
                    float* orow = out + (size_t)grow * 128;
#pragma unroll
                    for (int t = 0; t < 8; ++t) {
                        float v = acc[m][t][r] * inv;
                        orow[t * 16 + fr] = (v > 0.f) ? v : expm1f(v);
                    }
                }
            }
        }
    }
}

// ---------- K3: sum partials, divide by Z, ELU ----------
__global__ __launch_bounds__(256) void k3_fin(
        const float* __restrict__ pvp, const float* __restrict__ zp,
        float* __restrict__ out, int jsplit) {
    const int idx = blockIdx.x * 256 + threadIdx.x;
    const int row = idx >> 5;
    const int c = (idx & 31) << 2;
    f32x4 s = zero4();
    float z = 0.f;
    for (int p = 0; p < jsplit; ++p) {
        s += *(const f32x4*)(pvp + ((size_t)p * NN + row) * 128 + c);
        z += zp[(size_t)p * NN + row];
    }
    const float inv = 1.0f / z;
    f32x4 o;
#pragma unroll
    for (int e = 0; e < 4; ++e) {
        float v = s[e] * inv;
        o[e] = (v > 0.f) ? v : expm1f(v);
    }
    *(f32x4*)(out + (size_t)row * 128 + c) = o;
}

extern "C" void kernel_launch(void* const* d_in, const int* in_sizes, int n_in,
                              void* d_out, int out_size, void* d_ws, size_t ws_size,
                              hipStream_t stream) {
    const float* x   = (const float*)d_in[0];   // 8192 x 256
    const float* W   = (const float*)d_in[1];   // 256 x 128
    const float* a   = (const float*)d_in[2];   // 256
    const int*   adj = (const int*)d_in[3];     // 8192 x 8192
    float* out = (float*)d_out;                 // 8192 x 128

    char* ws = (char*)d_ws;
    const size_t MB = 1024 * 1024;
    short* hTb   = (short*)ws;                        // 2 MB (j-blocked)
    float* s1L2E = (float*)(ws + 2 * MB);             // 32 KB
    float* s2L2E = (float*)(ws + 2 * MB + 32768);     // 32 KB
    short* WT    = (short*)(ws + 2 * MB + 65536);     // 64 KB
    const size_t base = 2 * MB + 131072;

    auto need = [&](size_t js) {
        return base + js * ((size_t)NN * 128 * 4) + js * ((size_t)NN * 4);
    };
    int jsplit;
    if (ws_size >= need(2)) jsplit = 2;
    else if (ws_size >= need(1)) jsplit = 1;
    else jsplit = 0;

    float* pvp = (float*)(ws + base);
    float* zp  = (float*)(ws + base + (size_t)(jsplit > 0 ? jsplit : 1) * NN * 128 * 4);

    k0_wt<<<128, 256, 0, stream>>>(W, WT);
    k1_h<<<256, 128, 0, stream>>>(x, WT, a, hTb, s1L2E, s2L2E);

    if (jsplit == 2) {
        k2_attn<2, true><<<512, 256, 0, stream>>>(adj, hTb, s1L2E, s2L2E, pvp, zp, nullptr);
        k3_fin<<<1024, 256, 0, stream>>>(pvp, zp, out, 2);
    } else if (jsplit == 1) {
        k2_attn<1, true><<<256, 256, 0, stream>>>(adj, hTb, s1L2E, s2L2E, pvp, zp, nullptr);
        k3_fin<<<1024, 256, 0, stream>>>(pvp, zp, out, 1);
    } else {
        k2_attn<1, false><<<256, 256, 0, stream>>>(adj, hTb, s1L2E, s2L2E, nullptr, nullptr, out);
    }
}

// Round 19
// 82.456 us; speedup vs baseline: 1.4191x; 1.4191x over previous
//
#include <hip/hip_runtime.h>
#include <math.h>

#define NN 8192

typedef __attribute__((ext_vector_type(8))) short short8;
typedef __attribute__((ext_vector_type(4))) short short4v;
typedef __attribute__((ext_vector_type(4))) float f32x4;
typedef __attribute__((ext_vector_type(4))) int int4v;

#define L2E 1.4426950408889634f

typedef __attribute__((address_space(3))) unsigned lds_u32;
typedef __attribute__((address_space(1))) unsigned g_u32;

__device__ __forceinline__ void gll16(const void* g, void* l) {
    __builtin_amdgcn_global_load_lds((const g_u32*)g, (lds_u32*)l, 16, 0, 0);
}

__device__ __forceinline__ short f2bf(float f) {
    union { float f; unsigned u; } v; v.f = f;
    unsigned r = v.u + 0x7fffu + ((v.u >> 16) & 1u);
    return (short)(r >> 16);
}

__device__ __forceinline__ f32x4 zero4() {
    f32x4 v; v[0] = 0.f; v[1] = 0.f; v[2] = 0.f; v[3] = 0.f; return v;
}

// ---------- K0: WT[f][k] = bf16(W[k][f]) ----------
__global__ void k0_wt(const float* __restrict__ W, short* __restrict__ WT) {
    int idx = blockIdx.x * 256 + threadIdx.x;
    if (idx < 256 * 128) {
        int k = idx & 255;
        int f = idx >> 8;
        WT[f * 256 + k] = f2bf(W[k * 128 + f]);
    }
}

// ---------- K1: h = x@W (bf16 MFMA); s1L2E/s2L2E; hTb j-blocked ----------
// hTb layout: [j/64][128 f][j%64] bf16 -> each (all-f x 64-j) tile is 16KB
// CONTIGUOUS (R17-verified).
__global__ __launch_bounds__(128) void k1_h(
        const float* __restrict__ x, const short* __restrict__ WT,
        const float* __restrict__ a, short* __restrict__ hTb,
        float* __restrict__ s1L2E, float* __restrict__ s2L2E) {
    const int w = threadIdx.x >> 6;
    const int l = threadIdx.x & 63;
    const int quad = l >> 4;
    const int fr = l & 15;
    const int i0 = blockIdx.x * 32 + w * 16;

    f32x4 acc[8];
#pragma unroll
    for (int t = 0; t < 8; ++t) acc[t] = zero4();

    const float* xrow = x + (size_t)(i0 + fr) * 256;
#pragma unroll
    for (int kk = 0; kk < 8; ++kk) {
        const int k0 = kk * 32 + quad * 8;
        f32x4 xa = *(const f32x4*)(xrow + k0);
        f32x4 xb = *(const f32x4*)(xrow + k0 + 4);
        short8 av;
#pragma unroll
        for (int e = 0; e < 4; ++e) { av[e] = f2bf(xa[e]); av[4 + e] = f2bf(xb[e]); }
#pragma unroll
        for (int t = 0; t < 8; ++t) {
            short8 bv = *(const short8*)(WT + (t * 16 + fr) * 256 + k0);
            acc[t] = __builtin_amdgcn_mfma_f32_16x16x32_bf16(av, bv, acc[t], 0, 0, 0);
        }
    }

    float s1p[4] = {0.f, 0.f, 0.f, 0.f};
    float s2p[4] = {0.f, 0.f, 0.f, 0.f};
#pragma unroll
    for (int t = 0; t < 8; ++t) {
        float a1v = a[t * 16 + fr];
        float a2v = a[128 + t * 16 + fr];
#pragma unroll
        for (int r = 0; r < 4; ++r) {
            s1p[r] += acc[t][r] * a1v;
            s2p[r] += acc[t][r] * a2v;
        }
    }
#pragma unroll
    for (int r = 0; r < 4; ++r) {
#pragma unroll
        for (int m = 1; m < 16; m <<= 1) {
            s1p[r] += __shfl_xor(s1p[r], m, 64);
            s2p[r] += __shfl_xor(s2p[r], m, 64);
        }
    }
    if (fr == 0) {
#pragma unroll
        for (int r = 0; r < 4; ++r) {
            const int i = i0 + quad * 4 + r;
            s1L2E[i] = s1p[r] * L2E;
            s2L2E[i] = s2p[r] * L2E;
        }
    }

    // blocked write: i within [i0, i0+16) lies in ONE 64-block (i0 mult of 16)
    {
        const size_t tbase = (size_t)(i0 >> 6) * 8192 + (i0 & 63) + quad * 4;
#pragma unroll
        for (int t = 0; t < 8; ++t) {
            short4v hv;
#pragma unroll
            for (int r = 0; r < 4; ++r) hv[r] = f2bf(acc[t][r]);
            *(short4v*)(hTb + tbase + (size_t)(t * 16 + fr) * 64) = hv;
        }
    }
}

// ---------- K2: 64-row blocks, all-gll counted-vmcnt pipeline (R14/R17 regime) ----------
// R14 structure (verified) with j-blocked hTb sources: each hT gll = 1KB
// CONTIGUOUS (bank swizzle = 16B-unit permutation within the chunk;
// read-side XOR unchanged). adj staging / vmcnt(9) ledger (pure-gll loop,
// sound) / barriers / epilogue all R14-verbatim.
template<int JSPLIT, bool PARTIAL>
__global__ __launch_bounds__(256, 2) void k2_attn(
        const int* __restrict__ adj, const short* __restrict__ hTb,
        const float* __restrict__ s1g, const float* __restrict__ s2g,
        float* __restrict__ pvp, float* __restrict__ zp,
        float* __restrict__ out) {
    constexpr int JW = NN / JSPLIT;
    constexpr int NSTEP = JW / 64;
    constexpr int BUFB = 33792;            // hT 16K | adj 16K | c 1K
    __shared__ __align__(16) char lds_c[2 * BUFB + 512];

    const int tid = threadIdx.x;
    const int w = tid >> 6;
    const int l = tid & 63;
    const int quad = l >> 4;
    const int fr = l & 15;
    const int rh = w >> 1;
    const int wj = w & 1;
    const int rb = blockIdx.x / JSPLIT;
    const int jb = blockIdx.x % JSPLIT;
    const int r64 = rb * 64;
    const int jbb = jb * JW;

    const float S0 = s1g[r64 + rh * 32 + fr];        // m-tile 0 rows
    const float S1 = s1g[r64 + rh * 32 + 16 + fr];   // m-tile 1 rows

    // ---- pre-swizzled gll sources (linear LDS dest) ----
    const char* hsrc[4];
    const char* asrc[4];
    {
        const char* hbase = (const char*)hTb + (size_t)(jbb >> 6) * 16384;
        const char* abase = (const char*)adj;
#pragma unroll
        for (int p = 0; p < 4; ++p) {
            const int off = w * 4096 + p * 1024 + l * 16;
            {   // hTb tile: 16KB contiguous; swizzle permutes 16B units in-row
                const int row = off >> 7;
                hsrc[p] = hbase + (off ^ ((row & 7) << 4));
            }
            {   // adj region: 256B per adj row (64 cols x 4B)
                const int row = off >> 8;
                const int colb = off & 255;
                asrc[p] = abase + (size_t)(r64 + row) * (NN * 4) + (size_t)jbb * 4
                        + (colb ^ ((row & 7) << 4));
            }
        }
    }
    const char* csrc = (const char*)s2g + (size_t)jbb * 4 + l * 16;

    auto STAGE = [&](int jt, int buf) {
        jt = (jt < NSTEP) ? jt : NSTEP - 1;           // tail clamp (junk, uniform count)
        char* hd = lds_c + buf * BUFB + w * 4096;
        char* ad = lds_c + buf * BUFB + 16384 + w * 4096;
        char* cd = lds_c + buf * BUFB + 32768;
        const size_t hof = (size_t)jt * 16384;        // blocked: 16KB per j-tile
        const size_t aof = (size_t)jt * 256;
#pragma unroll
        for (int p = 0; p < 4; ++p) gll16(hsrc[p] + hof, hd + p * 1024);
#pragma unroll
        for (int p = 0; p < 4; ++p) gll16(asrc[p] + aof, ad + p * 1024);
        gll16(csrc + aof, cd);                        // benign 4-wave WAW
    };

    f32x4 acc[2][8];
#pragma unroll
    for (int m = 0; m < 2; ++m)
#pragma unroll
        for (int t = 0; t < 8; ++t) acc[m][t] = zero4();
    float zacc0 = 0.f, zacc1 = 0.f;

    // prologue: 2 tiles in flight (18 gll/wave)
    STAGE(0, 0); STAGE(1, 1);

    const int ar0 = rh * 32 + fr;
    const int ar1 = rh * 32 + 16 + fr;
    const unsigned aswz = (unsigned)((ar0 & 7) << 4);   // (ar1&7)==(ar0&7)
    const unsigned a0 = (unsigned)(ar0 * 256 + wj * 128 + quad * 32);
    const unsigned a1 = (unsigned)(ar1 * 256 + wj * 128 + quad * 32);

    for (int t = 0; t < NSTEP; ++t) {
        const int cur = t & 1;
        // stage(t) ready once only stage(t+1)'s 9 gll remain outstanding
        asm volatile("s_waitcnt vmcnt(9)" ::: "memory");
        __builtin_amdgcn_s_barrier();
        __builtin_amdgcn_sched_barrier(0);

        const char* hb = lds_c + cur * BUFB;
        const char* ab = lds_c + cur * BUFB + 16384;
        const float* cb = (const float*)(lds_c + cur * BUFB + 32768);

        const int4v g00 = *(const int4v*)(ab + (a0 ^ aswz));
        const int4v g01 = *(const int4v*)(ab + ((a0 + 16) ^ aswz));
        const int4v g10 = *(const int4v*)(ab + (a1 ^ aswz));
        const int4v g11 = *(const int4v*)(ab + ((a1 + 16) ^ aswz));
        const f32x4 c0 = *(const f32x4*)((const char*)cb + wj * 128 + quad * 32);
        const f32x4 c1 = *(const f32x4*)((const char*)cb + wj * 128 + quad * 32 + 16);

        short8 pa0, pa1;
        {
            float zs0 = 0.f, zs1 = 0.f;
#pragma unroll
            for (int e = 0; e < 8; ++e) {
                const float cv = (e < 4) ? c0[e] : c1[e - 4];
                const int gv0 = (e < 4) ? g00[e] : g01[e - 4];
                const int gv1 = (e < 4) ? g10[e] : g11[e - 4];
                const float u0 = S0 + cv;
                const float u1 = S1 + cv;
                const float t0 = fmaxf(u0, 0.2f * u0);   // lrelu in log2 space
                const float t1 = fmaxf(u1, 0.2f * u1);
                const float p0 = (gv0 > 0) ? exp2f(t0) : 0.f;
                const float p1 = (gv1 > 0) ? exp2f(t1) : 0.f;
                zs0 += p0; zs1 += p1;
                pa0[e] = f2bf(p0);
                pa1[e] = f2bf(p1);
            }
            zacc0 += zs0; zacc1 += zs1;
        }

#pragma unroll
        for (int t8 = 0; t8 < 8; ++t8) {
            const int hrow = t8 * 16 + fr;
            const short8 bv = *(const short8*)(
                hb + ((unsigned)(hrow * 128 + wj * 64 + quad * 16) ^ ((hrow & 7) << 4)));
            acc[0][t8] = __builtin_amdgcn_mfma_f32_16x16x32_bf16(pa0, bv, acc[0][t8], 0, 0, 0);
            acc[1][t8] = __builtin_amdgcn_mfma_f32_16x16x32_bf16(pa1, bv, acc[1][t8], 0, 0, 0);
        }

        __builtin_amdgcn_sched_barrier(0);
        __builtin_amdgcn_s_barrier();                 // all reads of buf cur done
        STAGE(t + 2, cur);                            // refill freed buffer
    }

    asm volatile("s_waitcnt vmcnt(0)" ::: "memory");  // drain junk tail stages
    __syncthreads();

    // ---- epilogue: z + acc reduction over wj (red aliases staging LDS) ----
    zacc0 += __shfl_xor(zacc0, 16, 64);
    zacc0 += __shfl_xor(zacc0, 32, 64);
    zacc1 += __shfl_xor(zacc1, 16, 64);
    zacc1 += __shfl_xor(zacc1, 32, 64);
    float* zb = (float*)(lds_c + 2 * BUFB);           // 128 floats
    if (l < 16) {
        zb[w * 32 + l] = zacc0;
        zb[w * 32 + 16 + l] = zacc1;
    }

    float* red = (float*)lds_c;                       // 2 regions x 16KB
    if (wj == 1) {
#pragma unroll
        for (int m = 0; m < 2; ++m)
#pragma unroll
            for (int t8 = 0; t8 < 8; ++t8)
                *(f32x4*)(red + rh * 4096 + (m * 8 + t8) * 256 + l * 4) = acc[m][t8];
    }
    __syncthreads();

    if (wj == 0) {
#pragma unroll
        for (int m = 0; m < 2; ++m)
#pragma unroll
            for (int t8 = 0; t8 < 8; ++t8)
                acc[m][t8] += *(const f32x4*)(red + rh * 4096 + (m * 8 + t8) * 256 + l * 4);
#pragma unroll
        for (int m = 0; m < 2; ++m) {
#pragma unroll
            for (int r = 0; r < 4; ++r) {
                const int rr = m * 16 + quad * 4 + r;            // row within wave's 32
                const float z = zb[(rh * 2 + 0) * 32 + rr] + zb[(rh * 2 + 1) * 32 + rr];
                const int grow = r64 + rh * 32 + rr;
                if (PARTIAL) {
                    if (fr == 0) zp[(size_t)jb * NN + grow] = z;
                    float* orow = pvp + ((size_t)jb * NN + grow) * 128;
#pragma unroll
                    for (int t8 = 0; t8 < 8; ++t8) orow[t8 * 16 + fr] = acc[m][t8][r];
                } else {
                    const float inv = 1.0f / z;
                    float* orow = out + (size_t)grow * 128;
#pragma unroll
                    for (int t8 = 0; t8 < 8; ++t8) {
                        float v = acc[m][t8][r] * inv;
                        orow[t8 * 16 + fr] = (v > 0.f) ? v : expm1f(v);
                    }
                }
            }
        }
    }
}

// ---------- K3: sum partials, divide by Z, ELU ----------
__global__ __launch_bounds__(256) void k3_fin(
        const float* __restrict__ pvp, const float* __restrict__ zp,
        float* __restrict__ out, int jsplit) {
    const int idx = blockIdx.x * 256 + threadIdx.x;
    const int row = idx >> 5;
    const int c = (idx & 31) << 2;
    f32x4 s = zero4();
    float z = 0.f;
    for (int p = 0; p < jsplit; ++p) {
        s += *(const f32x4*)(pvp + ((size_t)p * NN + row) * 128 + c);
        z += zp[(size_t)p * NN + row];
    }
    const float inv = 1.0f / z;
    f32x4 o;
#pragma unroll
    for (int e = 0; e < 4; ++e) {
        float v = s[e] * inv;
        o[e] = (v > 0.f) ? v : expm1f(v);
    }
    *(f32x4*)(out + (size_t)row * 128 + c) = o;
}

extern "C" void kernel_launch(void* const* d_in, const int* in_sizes, int n_in,
                              void* d_out, int out_size, void* d_ws, size_t ws_size,
                              hipStream_t stream) {
    const float* x   = (const float*)d_in[0];   // 8192 x 256
    const float* W   = (const float*)d_in[1];   // 256 x 128
    const float* a   = (const float*)d_in[2];   // 256
    const int*   adj = (const int*)d_in[3];     // 8192 x 8192
    float* out = (float*)d_out;                 // 8192 x 128

    char* ws = (char*)d_ws;
    const size_t MB = 1024 * 1024;
    short* hTb   = (short*)ws;                        // 2 MB (j-blocked)
    float* s1L2E = (float*)(ws + 2 * MB);             // 32 KB
    float* s2L2E = (float*)(ws + 2 * MB + 32768);     // 32 KB
    short* WT    = (short*)(ws + 2 * MB + 65536);     // 64 KB
    const size_t base = 2 * MB + 131072;

    auto need = [&](size_t js) {
        return base + js * ((size_t)NN * 128 * 4) + js * ((size_t)NN * 4);
    };
    int jsplit;
    if (ws_size >= need(4)) jsplit = 4;
    else if (ws_size >= need(2)) jsplit = 2;
    else if (ws_size >= need(1)) jsplit = 1;
    else jsplit = 0;

    float* pvp = (float*)(ws + base);
    float* zp  = (float*)(ws + base + (size_t)(jsplit > 0 ? jsplit : 1) * NN * 128 * 4);

    k0_wt<<<128, 256, 0, stream>>>(W, WT);
    k1_h<<<256, 128, 0, stream>>>(x, WT, a, hTb, s1L2E, s2L2E);

    if (jsplit == 4) {
        k2_attn<4, true><<<512, 256, 0, stream>>>(adj, hTb, s1L2E, s2L2E, pvp, zp, nullptr);
        k3_fin<<<1024, 256, 0, stream>>>(pvp, zp, out, 4);
    } else if (jsplit == 2) {
        k2_attn<2, true><<<256, 256, 0, stream>>>(adj, hTb, s1L2E, s2L2E, pvp, zp, nullptr);
        k3_fin<<<1024, 256, 0, stream>>>(pvp, zp, out, 2);
    } else if (jsplit == 1) {
        k2_attn<1, true><<<128, 256, 0, stream>>>(adj, hTb, s1L2E, s2L2E, pvp, zp, nullptr);
        k3_fin<<<1024, 256, 0, stream>>>(pvp, zp, out, 1);
    } else {
        k2_attn<1, false><<<128, 256, 0, stream>>>(adj, hTb, s1L2E, s2L2E, nullptr, nullptr, out);
    }
}